// Round 19
// baseline (522.303 us; speedup 1.0000x reference)
//
#include <hip/hip_runtime.h>
#include <stdint.h>

// PointNet SA via MFMA, v14: WAVE-AUTONOMOUS, ZERO BARRIERS.
// Each wave owns 16 points end-to-end with a private 8KB LDS slice (same-wave
// LDS ops are in-order; no __syncthreads anywhere). Stage-g operands direct
// from featT (L3-resident). s=32 pool spans 2 waves -> atomicMax on uint bits
// (relu>=0) into a zeroed output. 4 independent waves/block, 32KB LDS/block.
// Diagnosis: v6/v10/v13 all ~184us with no pipe >27% -> barrier convoy is the
// limiter; this removes ALL intra-block coupling.

namespace {
constexpr int kB = 4, kN = 16384, kC = 103, kP = 2048, kS = 32;

using short8 = __attribute__((ext_vector_type(8))) short;
using short4 = __attribute__((ext_vector_type(4))) short;
using f32x4  = __attribute__((ext_vector_type(4))) float;

constexpr int WG_HI = 0,     WG_LO = 8192;     // 64 x 128
constexpr int W1_HI = 16384, W1_LO = 20480;    // 64 x 64
constexpr int W2_HI = 24576, W2_LO = 32768;    // 128 x 64
constexpr int W3_HI = 40960, W3_LO = 73728;    // 256 x 128
constexpr size_t FT_OFF    = 262144;
constexpr size_t FT_SHORTS = (size_t)kB * kN * 128;
constexpr size_t WS_NEED   = FT_OFF + 2 * FT_SHORTS * 2;

__device__ __forceinline__ unsigned short f2bf(float x) {
    unsigned u = __float_as_uint(x);
    u += 0x7fffu + ((u >> 16) & 1u);           // RNE
    return (unsigned short)(u >> 16);
}
__device__ __forceinline__ float bf2f(unsigned short h) {
    return __uint_as_float((unsigned)h << 16);
}
__device__ __forceinline__ unsigned cvtpk(float a, float b) {
    unsigned r;
    asm("v_cvt_pk_bf16_f32 %0, %1, %2" : "=v"(r) : "v"(a), "v"(b));
    return r;
}
__device__ __forceinline__ void pack4(const float v[4], uint2& H, uint2& L) {
    H.x = cvtpk(v[0], v[1]);
    H.y = cvtpk(v[2], v[3]);
    const float r0 = v[0] - __uint_as_float(H.x << 16);
    const float r1 = v[1] - __uint_as_float(H.x & 0xffff0000u);
    const float r2 = v[2] - __uint_as_float(H.y << 16);
    const float r3 = v[3] - __uint_as_float(H.y & 0xffff0000u);
    L.x = cvtpk(r0, r1);
    L.y = cvtpk(r2, r3);
}

__global__ void copy_newxyz(const float* __restrict__ src, float* __restrict__ dst, int n) {
    int i = blockIdx.x * blockDim.x + threadIdx.x;
    if (i < n) dst[i] = src[i];
}

__global__ void prep_weights(const float* __restrict__ Wg, const float* __restrict__ W1,
                             const float* __restrict__ W2, const float* __restrict__ W3,
                             short* __restrict__ ws) {
    int i = blockIdx.x * blockDim.x + threadIdx.x;
    if (i >= 53248) return;
    float w; int hi, lo, j;
    if (i < 8192)       { j = i;         int o = j >> 7, c = j & 127; w = (c < 106) ? Wg[o * 106 + c] : 0.f; hi = WG_HI; lo = WG_LO; }
    else if (i < 12288) { j = i - 8192;  int o = j >> 6, c = j & 63;  w = W1[o * 64 + c];  hi = W1_HI; lo = W1_LO; }
    else if (i < 20480) { j = i - 12288; int o = j >> 6, c = j & 63;  w = W2[o * 64 + c];  hi = W2_HI; lo = W2_LO; }
    else                { j = i - 20480; int o = j >> 7, c = j & 127; w = W3[o * 128 + c]; hi = W3_HI; lo = W3_LO; }
    unsigned short h = f2bf(w);
    ws[hi + j] = (short)h;
    ws[lo + j] = (short)f2bf(w - bf2f(h));
}

__global__ __launch_bounds__(512) void prep_feat(const float* __restrict__ f,
                                                 short* __restrict__ ftH, short* __restrict__ ftL) {
    __shared__ float tile[kC][65];
    const int bb = blockIdx.x >> 8;
    const int n0 = (blockIdx.x & 255) * 64;
    const int tid = threadIdx.x;
    for (int c = tid >> 6; c < kC; c += 8)
        tile[c][tid & 63] = f[((size_t)bb * kC + c) * kN + n0 + (tid & 63)];
    __syncthreads();
    const int np = tid >> 3, gc = tid & 7;
    short* rH = ftH + ((size_t)bb * kN + n0 + np) * 128;
    short* rL = ftL + ((size_t)bb * kN + n0 + np) * 128;
    #pragma unroll
    for (int kk = 0; kk < 2; ++kk) {
        const int chunk = gc + 8 * kk;
        union { uint4 u; short s[8]; } H, L;
        #pragma unroll
        for (int e = 0; e < 8; ++e) {
            const int col = chunk * 8 + e;
            float v = (col >= 3 && col < 106) ? tile[col - 3][np] : 0.f;
            unsigned short hh = f2bf(v);
            H.s[e] = (short)hh;
            L.s[e] = (short)f2bf(v - bf2f(hh));
        }
        *(uint4*)(rH + chunk * 8) = H.u;
        *(uint4*)(rL + chunk * 8) = L.u;
    }
}

// ---------------- wave-autonomous kernel ----------------
// A: m=lane&15 (W row), k=8*(lane>>4)+j; B: n=lane&15 (point), same k;
// D: n=lane&15 (point), m=4*(lane>>4)+r  (verified maps, unchanged).
__global__ __launch_bounds__(256, 4) void pointnet_sa_wave(
    const float* __restrict__ xyz, const float* __restrict__ new_xyz,
    const int* __restrict__ idx,
    const short* __restrict__ ws, const short* __restrict__ ftH, const short* __restrict__ ftL,
    const float* __restrict__ bg, const float* __restrict__ b1f,
    const float* __restrict__ b2f, const float* __restrict__ b3f,
    float* __restrict__ out_pooled)  // (B, 256, P), PRE-ZEROED
{
    __shared__ alignas(16) short smem[16384];   // 32 KB = 4 waves x 8 KB private
    const int tid = threadIdx.x, lane = tid & 63, wave = tid >> 6;
    short* R   = smem + wave * 4096;            // this wave's slice (shorts)
    short* X0h = R;                              // [16][64]
    short* X0l = R + 1024;
    short* X1h = R + 2048;                       // [16][64]
    short* X1l = R + 3072;
    short* X2h = R;                              // [16][128] alias X0h|X0l
    short* X2l = R + 2048;                       // [16][128] alias X1h|X1l

    const int q = lane >> 4, n16 = lane & 15;
    const int wgid = blockIdx.x * 4 + wave;
    const int pt0  = wgid * 16;                  // 16 pts, all same (b, p)
    const int b    = pt0 >> 16;
    const int g    = pt0 >> 5;                   // flat b*P + p
    const int p_col = g & (kP - 1);
    const int n_pt = idx[pt0 + n16];
    const short* rH = ftH + ((size_t)b * kN + n_pt) * 128;
    const short* rL = ftL + ((size_t)b * kN + n_pt) * 128;

    float xd0 = 0.f, xd1 = 0.f, xd2 = 0.f;
    if (q == 0) {
        const float* xp = xyz + ((size_t)b * kN + n_pt) * 3;
        const float* np = new_xyz + ((size_t)b * kP + p_col) * 3;
        xd0 = xp[0] - np[0]; xd1 = xp[1] - np[1]; xd2 = xp[2] - np[2];
    }

    // ======== stage g: B-frags direct from featT, patch ch0-2 ========
    {
        short8 gbh[4], gbl[4];
        #pragma unroll
        for (int kt = 0; kt < 4; ++kt) {
            gbh[kt] = *(const short8*)(rH + kt * 32 + q * 8);
            gbl[kt] = *(const short8*)(rL + kt * 32 + q * 8);
        }
        if (q == 0) {
            const unsigned short h0 = f2bf(xd0), h1 = f2bf(xd1), h2 = f2bf(xd2);
            gbh[0][0] = (short)h0; gbh[0][1] = (short)h1; gbh[0][2] = (short)h2;
            gbl[0][0] = (short)f2bf(xd0 - bf2f(h0));
            gbl[0][1] = (short)f2bf(xd1 - bf2f(h1));
            gbl[0][2] = (short)f2bf(xd2 - bf2f(h2));
        }
        f32x4 ag[4];
        #pragma unroll
        for (int o = 0; o < 4; ++o) ag[o] = *(const f32x4*)(bg + o * 16 + 4 * q);
        #pragma unroll
        for (int o = 0; o < 4; ++o) {
            #pragma unroll
            for (int kt = 0; kt < 4; ++kt) {
                const size_t we = (size_t)(o * 16 + n16) * 128 + kt * 32 + q * 8;
                const short8 ah = *(const short8*)(ws + WG_HI + we);
                const short8 al = *(const short8*)(ws + WG_LO + we);
                ag[o] = __builtin_amdgcn_mfma_f32_16x16x32_bf16(ah, gbh[kt], ag[o], 0, 0, 0);
                ag[o] = __builtin_amdgcn_mfma_f32_16x16x32_bf16(ah, gbl[kt], ag[o], 0, 0, 0);
                ag[o] = __builtin_amdgcn_mfma_f32_16x16x32_bf16(al, gbh[kt], ag[o], 0, 0, 0);
            }
        }
        // gate: x0 = base*(1+w), base from featT (ch<3 patched with raw xd)
        #pragma unroll
        for (int o = 0; o < 4; ++o) {
            const uint2 BH = *(const uint2*)(rH + o * 16 + 4 * q);
            const uint2 BL = *(const uint2*)(rL + o * 16 + 4 * q);
            float base[4];
            base[0] = __uint_as_float(BH.x << 16)         + __uint_as_float(BL.x << 16);
            base[1] = __uint_as_float(BH.x & 0xffff0000u) + __uint_as_float(BL.x & 0xffff0000u);
            base[2] = __uint_as_float(BH.y << 16)         + __uint_as_float(BL.y << 16);
            base[3] = __uint_as_float(BH.y & 0xffff0000u) + __uint_as_float(BL.y & 0xffff0000u);
            if (o == 0 && q == 0) { base[0] = xd0; base[1] = xd1; base[2] = xd2; }
            float v[4];
            #pragma unroll
            for (int r = 0; r < 4; ++r) v[r] = fmaf(base[r], ag[o][r], base[r]);
            uint2 H, L;
            pack4(v, H, L);
            const int ck = (2 * o + (q >> 1)) ^ (n16 & 7);         // 16B chunk swizzle
            *(uint2*)(X0h + n16 * 64 + ck * 8 + (q & 1) * 4) = H;
            *(uint2*)(X0l + n16 * 64 + ck * 8 + (q & 1) * 4) = L;
        }
    }

    // ======== stage 1: x1 = relu(W1*x0 + b1) ========
    {
        short8 sbh[2], sbl[2];
        #pragma unroll
        for (int kt = 0; kt < 2; ++kt) {
            const int ck = (4 * kt + q) ^ (n16 & 7);
            sbh[kt] = *(const short8*)(X0h + n16 * 64 + ck * 8);
            sbl[kt] = *(const short8*)(X0l + n16 * 64 + ck * 8);
        }
        f32x4 a1[4];
        #pragma unroll
        for (int o = 0; o < 4; ++o) a1[o] = *(const f32x4*)(b1f + o * 16 + 4 * q);
        #pragma unroll
        for (int o = 0; o < 4; ++o) {
            #pragma unroll
            for (int kt = 0; kt < 2; ++kt) {
                const size_t we = (size_t)(o * 16 + n16) * 64 + kt * 32 + q * 8;
                const short8 ah = *(const short8*)(ws + W1_HI + we);
                const short8 al = *(const short8*)(ws + W1_LO + we);
                a1[o] = __builtin_amdgcn_mfma_f32_16x16x32_bf16(ah, sbh[kt], a1[o], 0, 0, 0);
                a1[o] = __builtin_amdgcn_mfma_f32_16x16x32_bf16(ah, sbl[kt], a1[o], 0, 0, 0);
                a1[o] = __builtin_amdgcn_mfma_f32_16x16x32_bf16(al, sbh[kt], a1[o], 0, 0, 0);
            }
        }
        #pragma unroll
        for (int o = 0; o < 4; ++o) {
            float v[4];
            #pragma unroll
            for (int r = 0; r < 4; ++r) v[r] = fmaxf(a1[o][r], 0.f);
            uint2 H, L;
            pack4(v, H, L);
            const int ck = (2 * o + (q >> 1)) ^ (n16 & 7);
            *(uint2*)(X1h + n16 * 64 + ck * 8 + (q & 1) * 4) = H;
            *(uint2*)(X1l + n16 * 64 + ck * 8 + (q & 1) * 4) = L;
        }
    }

    // ======== stage 2: x2 = relu(W2*x1 + b2); X2 aliases X0|X1 ========
    {
        short8 sbh[2], sbl[2];
        #pragma unroll
        for (int kt = 0; kt < 2; ++kt) {
            const int ck = (4 * kt + q) ^ (n16 & 7);
            sbh[kt] = *(const short8*)(X1h + n16 * 64 + ck * 8);
            sbl[kt] = *(const short8*)(X1l + n16 * 64 + ck * 8);
        }
        f32x4 a2[8];
        #pragma unroll
        for (int o = 0; o < 8; ++o) a2[o] = *(const f32x4*)(b2f + o * 16 + 4 * q);
        #pragma unroll
        for (int o = 0; o < 8; ++o) {
            #pragma unroll
            for (int kt = 0; kt < 2; ++kt) {
                const size_t we = (size_t)(o * 16 + n16) * 64 + kt * 32 + q * 8;
                const short8 ah = *(const short8*)(ws + W2_HI + we);
                const short8 al = *(const short8*)(ws + W2_LO + we);
                a2[o] = __builtin_amdgcn_mfma_f32_16x16x32_bf16(ah, sbh[kt], a2[o], 0, 0, 0);
                a2[o] = __builtin_amdgcn_mfma_f32_16x16x32_bf16(ah, sbl[kt], a2[o], 0, 0, 0);
                a2[o] = __builtin_amdgcn_mfma_f32_16x16x32_bf16(al, sbh[kt], a2[o], 0, 0, 0);
            }
        }
        // writes overwrite X0|X1 regions; safe: values depend on all X1 reads
        #pragma unroll
        for (int o = 0; o < 8; ++o) {
            float v[4];
            #pragma unroll
            for (int r = 0; r < 4; ++r) v[r] = fmaxf(a2[o][r], 0.f);
            uint2 H, L;
            pack4(v, H, L);
            const int ck = (2 * o + (q >> 1)) ^ (n16 & 15);        // 16 chunks/row
            *(uint2*)(X2h + n16 * 128 + ck * 8 + (q & 1) * 4) = H;
            *(uint2*)(X2l + n16 * 128 + ck * 8 + (q & 1) * 4) = L;
        }
    }

    // ======== stage 3: 256 outputs in 2 halves + pool + atomicMax ========
    {
        short8 sbh[4], sbl[4];
        #pragma unroll
        for (int kt = 0; kt < 4; ++kt) {
            const int ck = (4 * kt + q) ^ (n16 & 15);
            sbh[kt] = *(const short8*)(X2h + n16 * 128 + ck * 8);
            sbl[kt] = *(const short8*)(X2l + n16 * 128 + ck * 8);
        }
        float* outB = out_pooled + (size_t)(g >> 11) * 256 * kP;
        #pragma unroll
        for (int h = 0; h < 2; ++h) {
            f32x4 a3[8];
            #pragma unroll
            for (int o = 0; o < 8; ++o)
                a3[o] = *(const f32x4*)(b3f + (h * 8 + o) * 16 + 4 * q);
            #pragma unroll
            for (int o = 0; o < 8; ++o) {
                #pragma unroll
                for (int kt = 0; kt < 4; ++kt) {
                    const size_t we = (size_t)((h * 8 + o) * 16 + n16) * 128 + kt * 32 + q * 8;
                    const short8 ah = *(const short8*)(ws + W3_HI + we);
                    const short8 al = *(const short8*)(ws + W3_LO + we);
                    a3[o] = __builtin_amdgcn_mfma_f32_16x16x32_bf16(ah, sbh[kt], a3[o], 0, 0, 0);
                    a3[o] = __builtin_amdgcn_mfma_f32_16x16x32_bf16(ah, sbl[kt], a3[o], 0, 0, 0);
                    a3[o] = __builtin_amdgcn_mfma_f32_16x16x32_bf16(al, sbh[kt], a3[o], 0, 0, 0);
                }
            }
            #pragma unroll
            for (int o = 0; o < 8; ++o) {
                #pragma unroll
                for (int r = 0; r < 4; ++r) {
                    float v = fmaxf(a3[o][r], 0.f);
                    v = fmaxf(v, __shfl_xor(v, 1, 16));
                    v = fmaxf(v, __shfl_xor(v, 2, 16));
                    v = fmaxf(v, __shfl_xor(v, 4, 16));
                    v = fmaxf(v, __shfl_xor(v, 8, 16));
                    if (n16 == 0) {
                        const int ch = (h * 8 + o) * 16 + 4 * q + r;
                        atomicMax((unsigned int*)(outB + (size_t)ch * kP + p_col),
                                  __float_as_uint(v));      // relu >= 0: uint order == float order
                    }
                }
            }
        }
    }
}

// ---------------- scalar fallback (barriers; only if ws too small) ----------------
__global__ __launch_bounds__(512, 2) void pointnet_sa_scalar(
    const float* __restrict__ xyz, const float* __restrict__ features,
    const float* __restrict__ new_xyz, const int* __restrict__ idx,
    const short* __restrict__ ws,
    const float* __restrict__ bg, const float* __restrict__ b1f,
    const float* __restrict__ b2f, const float* __restrict__ b3f,
    float* __restrict__ out_pooled)
{
    __shared__ alignas(16) short smem[24576];
    short* NFh = smem;          short* NFl = smem + 8192;    // [64][128]
    short* X0h = smem + 16384;  short* X0l = smem + 20480;   // [64][64]

    const int tid = threadIdx.x, lane = tid & 63, wave = tid >> 6;
    const int q = lane >> 4, n16 = lane & 15;
    const int pt0 = blockIdx.x * 64;
    const int b = pt0 >> 16;

    {
        const int p = tid & 63;
        const int cg = tid >> 6;
        const int pt = pt0 + p;
        const int n = idx[pt];
        const int pp = (pt >> 5) & (kP - 1);
        const float* fbp = features + (size_t)b * kC * kN + n;
        const float* xp = xyz + ((size_t)b * kN + n) * 3;
        const float* np = new_xyz + ((size_t)b * kP + pp) * 3;
        for (int c = cg; c < 128; c += 8) {
            float v;
            if (c < 3)        v = xp[c] - np[c];
            else if (c < 106) v = fbp[(size_t)(c - 3) * kN];
            else              v = 0.f;
            const unsigned short h = f2bf(v);
            const int cs = c ^ ((p & 7) << 3);
            NFh[p * 128 + cs] = (short)h;
            NFl[p * 128 + cs] = (short)f2bf(v - bf2f(h));
        }
    }
    __syncthreads();
    const int ot = wave & 3, ptp = 2 * (wave >> 2);
    // stage g
    {
        f32x4 a[2];
        #pragma unroll
        for (int j = 0; j < 2; ++j) a[j] = *(const f32x4*)(bg + ot * 16 + 4 * q);
        #pragma unroll
        for (int kt = 0; kt < 4; ++kt) {
            const int k0 = kt * 32 + q * 8;
            #pragma unroll
            for (int j = 0; j < 2; ++j) {
                const int p = (ptp + j) * 16 + n16;
                const int e = p * 128 + (k0 ^ ((p & 7) << 3));
                const short8 bh = *(const short8*)(NFh + e);
                const short8 bl = *(const short8*)(NFl + e);
                const size_t we = (size_t)(ot * 16 + n16) * 128 + k0;
                const short8 ah = *(const short8*)(ws + WG_HI + we);
                const short8 al = *(const short8*)(ws + WG_LO + we);
                a[j] = __builtin_amdgcn_mfma_f32_16x16x32_bf16(ah, bh, a[j], 0, 0, 0);
                a[j] = __builtin_amdgcn_mfma_f32_16x16x32_bf16(ah, bl, a[j], 0, 0, 0);
                a[j] = __builtin_amdgcn_mfma_f32_16x16x32_bf16(al, bh, a[j], 0, 0, 0);
            }
        }
        const int ob = ot * 16 + 4 * q;
        #pragma unroll
        for (int j = 0; j < 2; ++j) {
            const int p = (ptp + j) * 16 + n16;
            const int cs = ob ^ ((p & 7) << 3);
            const short4 h4 = *(const short4*)(NFh + p * 128 + cs);
            const short4 l4 = *(const short4*)(NFl + p * 128 + cs);
            float v[4];
            #pragma unroll
            for (int r = 0; r < 4; ++r) {
                const float base = bf2f((unsigned short)h4[r]) + bf2f((unsigned short)l4[r]);
                v[r] = fmaf(base, a[j][r], base);
            }
            uint2 H, L;
            pack4(v, H, L);
            *(uint2*)(X0h + p * 64 + cs) = H;
            *(uint2*)(X0l + p * 64 + cs) = L;
        }
    }
    __syncthreads();
    // stage 1 -> X1 in NF cols 0-63
    {
        f32x4 a[2];
        #pragma unroll
        for (int j = 0; j < 2; ++j) a[j] = *(const f32x4*)(b1f + ot * 16 + 4 * q);
        #pragma unroll
        for (int kt = 0; kt < 2; ++kt) {
            const int k0 = kt * 32 + q * 8;
            #pragma unroll
            for (int j = 0; j < 2; ++j) {
                const int p = (ptp + j) * 16 + n16;
                const int e = p * 64 + (k0 ^ ((p & 7) << 3));
                const short8 bh = *(const short8*)(X0h + e);
                const short8 bl = *(const short8*)(X0l + e);
                const size_t we = (size_t)(ot * 16 + n16) * 64 + k0;
                const short8 ah = *(const short8*)(ws + W1_HI + we);
                const short8 al = *(const short8*)(ws + W1_LO + we);
                a[j] = __builtin_amdgcn_mfma_f32_16x16x32_bf16(ah, bh, a[j], 0, 0, 0);
                a[j] = __builtin_amdgcn_mfma_f32_16x16x32_bf16(ah, bl, a[j], 0, 0, 0);
                a[j] = __builtin_amdgcn_mfma_f32_16x16x32_bf16(al, bh, a[j], 0, 0, 0);
            }
        }
        const int ob = ot * 16 + 4 * q;
        #pragma unroll
        for (int j = 0; j < 2; ++j) {
            const int p = (ptp + j) * 16 + n16;
            const int cs = ob ^ ((p & 7) << 3);
            float v[4];
            #pragma unroll
            for (int r = 0; r < 4; ++r) v[r] = fmaxf(a[j][r], 0.f);
            uint2 H, L;
            pack4(v, H, L);
            *(uint2*)(NFh + p * 128 + cs) = H;
            *(uint2*)(NFl + p * 128 + cs) = L;
        }
    }
    __syncthreads();
    // stage 2 -> X2 split (X0 region cols 0-63 | NF cols 64-127)
    {
        f32x4 a[2][2];
        #pragma unroll
        for (int i = 0; i < 2; ++i)
            #pragma unroll
            for (int j = 0; j < 2; ++j)
                a[i][j] = *(const f32x4*)(b2f + (2 * (wave & 3) + i) * 16 + 4 * q);
        #pragma unroll
        for (int kt = 0; kt < 2; ++kt) {
            const int k0 = kt * 32 + q * 8;
            #pragma unroll
            for (int j = 0; j < 2; ++j) {
                const int p = (ptp + j) * 16 + n16;
                const int e = p * 128 + (k0 ^ ((p & 7) << 3));
                const short8 bh = *(const short8*)(NFh + e);
                const short8 bl = *(const short8*)(NFl + e);
                #pragma unroll
                for (int i = 0; i < 2; ++i) {
                    const size_t we = (size_t)((2 * (wave & 3) + i) * 16 + n16) * 64 + k0;
                    const short8 ah = *(const short8*)(ws + W2_HI + we);
                    const short8 al = *(const short8*)(ws + W2_LO + we);
                    a[i][j] = __builtin_amdgcn_mfma_f32_16x16x32_bf16(ah, bh, a[i][j], 0, 0, 0);
                    a[i][j] = __builtin_amdgcn_mfma_f32_16x16x32_bf16(ah, bl, a[i][j], 0, 0, 0);
                    a[i][j] = __builtin_amdgcn_mfma_f32_16x16x32_bf16(al, bh, a[i][j], 0, 0, 0);
                }
            }
        }
        __syncthreads();
        #pragma unroll
        for (int i = 0; i < 2; ++i) {
            const int oo = 2 * (wave & 3) + i;
            const int ob = (oo & 3) * 16 + 4 * q;
            #pragma unroll
            for (int j = 0; j < 2; ++j) {
                const int p = (ptp + j) * 16 + n16;
                const int cs = ob ^ ((p & 7) << 3);
                float v[4];
                #pragma unroll
                for (int r = 0; r < 4; ++r) v[r] = fmaxf(a[i][j][r], 0.f);
                uint2 H, L;
                pack4(v, H, L);
                if (oo < 4) {
                    *(uint2*)(X0h + p * 64 + cs) = H;
                    *(uint2*)(X0l + p * 64 + cs) = L;
                } else {
                    *(uint2*)(NFh + 64 + p * 128 + cs) = H;
                    *(uint2*)(NFl + 64 + p * 128 + cs) = L;
                }
            }
        }
    }
    __syncthreads();
    // stage 3 + pool
    {
        f32x4 a[2][4];
        #pragma unroll
        for (int i = 0; i < 2; ++i)
            #pragma unroll
            for (int j = 0; j < 4; ++j)
                a[i][j] = *(const f32x4*)(b3f + (2 * wave + i) * 16 + 4 * q);
        #pragma unroll
        for (int kt = 0; kt < 2; ++kt) {
            const int k0 = kt * 32 + q * 8;
            #pragma unroll
            for (int j = 0; j < 4; ++j) {
                const int p = j * 16 + n16;
                const int e0 = p * 64 + (k0 ^ ((p & 7) << 3));
                const short8 bh0 = *(const short8*)(X0h + e0);
                const short8 bl0 = *(const short8*)(X0l + e0);
                const int e1 = p * 128 + (k0 ^ ((p & 7) << 3));
                const short8 bh1 = *(const short8*)(NFh + 64 + e1);
                const short8 bl1 = *(const short8*)(NFl + 64 + e1);
                #pragma unroll
                for (int i = 0; i < 2; ++i) {
                    const size_t w0 = (size_t)((2 * wave + i) * 16 + n16) * 128 + k0;
                    const size_t w1 = w0 + 64;
                    const short8 ah0 = *(const short8*)(ws + W3_HI + w0);
                    const short8 al0 = *(const short8*)(ws + W3_LO + w0);
                    const short8 ah1 = *(const short8*)(ws + W3_HI + w1);
                    const short8 al1 = *(const short8*)(ws + W3_LO + w1);
                    a[i][j] = __builtin_amdgcn_mfma_f32_16x16x32_bf16(ah0, bh0, a[i][j], 0, 0, 0);
                    a[i][j] = __builtin_amdgcn_mfma_f32_16x16x32_bf16(ah0, bl0, a[i][j], 0, 0, 0);
                    a[i][j] = __builtin_amdgcn_mfma_f32_16x16x32_bf16(al0, bh0, a[i][j], 0, 0, 0);
                    a[i][j] = __builtin_amdgcn_mfma_f32_16x16x32_bf16(ah1, bh1, a[i][j], 0, 0, 0);
                    a[i][j] = __builtin_amdgcn_mfma_f32_16x16x32_bf16(ah1, bl1, a[i][j], 0, 0, 0);
                    a[i][j] = __builtin_amdgcn_mfma_f32_16x16x32_bf16(al1, bh1, a[i][j], 0, 0, 0);
                }
            }
        }
        #pragma unroll
        for (int i = 0; i < 2; ++i)
            #pragma unroll
            for (int sg = 0; sg < 2; ++sg)
                #pragma unroll
                for (int r = 0; r < 4; ++r) {
                    float v = fmaxf(a[i][2 * sg][r], a[i][2 * sg + 1][r]);
                    v = fmaxf(v, __shfl_xor(v, 1, 16));
                    v = fmaxf(v, __shfl_xor(v, 2, 16));
                    v = fmaxf(v, __shfl_xor(v, 4, 16));
                    v = fmaxf(v, __shfl_xor(v, 8, 16));
                    v = fmaxf(v, 0.f);
                    if (n16 == 0) {
                        const int o = (2 * wave + i) * 16 + 4 * q + r;
                        const int g = (pt0 >> 5) + sg;
                        out_pooled[((size_t)(g >> 11) * 256 + o) * kP + (g & (kP - 1))] = v;
                    }
                }
    }
}
}  // namespace

extern "C" void kernel_launch(void* const* d_in, const int* in_sizes, int n_in,
                              void* d_out, int out_size, void* d_ws, size_t ws_size,
                              hipStream_t stream) {
    const float* xyz      = (const float*)d_in[0];
    const float* features = (const float*)d_in[1];
    const float* new_xyz  = (const float*)d_in[2];
    const int*   idx      = (const int*)d_in[3];
    const float* Wg = (const float*)d_in[4];
    const float* bg = (const float*)d_in[5];
    const float* W1 = (const float*)d_in[6];
    const float* b1 = (const float*)d_in[7];
    const float* W2 = (const float*)d_in[8];
    const float* b2 = (const float*)d_in[9];
    const float* W3 = (const float*)d_in[10];
    const float* b3 = (const float*)d_in[11];
    float* out = (float*)d_out;
    short* ws  = (short*)d_ws;
    short* ftH = (short*)((char*)d_ws + FT_OFF);
    short* ftL = ftH + FT_SHORTS;

    const int nxyz = kB * kP * 3;
    copy_newxyz<<<(nxyz + 255) / 256, 256, 0, stream>>>(new_xyz, out, nxyz);
    prep_weights<<<(53248 + 255) / 256, 256, 0, stream>>>(Wg, W1, W2, W3, ws);

    float* pooled = out + nxyz;
    if (ws_size >= WS_NEED) {
        hipMemsetAsync(pooled, 0, (size_t)kB * 256 * kP * sizeof(float), stream);
        prep_feat<<<kB * (kN / 64), 512, 0, stream>>>(features, ftH, ftL);
        pointnet_sa_wave<<<(kB * kP * kS) / 16 / 4, 256, 0, stream>>>(
            xyz, new_xyz, idx, ws, ftH, ftL, bg, b1, b2, b3, pooled);
    } else {
        pointnet_sa_scalar<<<(kB * kP * kS) / 64, 512, 0, stream>>>(
            xyz, features, new_xyz, idx, ws, bg, b1, b2, b3, pooled);
    }
}

// Round 20
// 469.106 us; speedup vs baseline: 1.1134x; 1.1134x over previous
//
#include <hip/hip_runtime.h>
#include <stdint.h>

// PointNet SA, v15: LAYERED STREAMING PIPELINE (one kernel per layer).
// Diagnosis across v10-v14: perf tracks global re-read traffic (weights/featT),
// not barriers/occupancy. Fused blocks force weight re-streaming per 64 pts.
// Fix: per-layer kernels; weights hoisted in regs ONCE per wave, amortized over
// 128-pt loops; activations stream via L3-resident planes in d_ws; no barriers,
// no LDS (K4 stages its W3 o-half in LDS once). Tiered fallback: v13 / scalar.

namespace {
constexpr int kB = 4, kN = 16384, kC = 103, kP = 2048, kS = 32;
constexpr int NPTS = kB * kP * kS;             // 262144

using short8 = __attribute__((ext_vector_type(8))) short;
using short4 = __attribute__((ext_vector_type(4))) short;
using f32x4  = __attribute__((ext_vector_type(4))) float;

constexpr int WG_HI = 0,     WG_LO = 8192;     // 64 x 128 (shorts)
constexpr int W1_HI = 16384, W1_LO = 20480;    // 64 x 64
constexpr int W2_HI = 24576, W2_LO = 32768;    // 128 x 64
constexpr int W3_HI = 40960, W3_LO = 73728;    // 256 x 128
// mid-tier (v13) layout
constexpr size_t FT_OFF    = 262144;
constexpr size_t FT_SHORTS = (size_t)kB * kN * 128;
constexpr size_t WS_NEED   = FT_OFF + 2 * FT_SHORTS * 2;
// layered layout (bytes): [weights][Z: ftH|ftL|x0H|x0L, overlaid later by x2H|x2L][x1H][x1L]
constexpr size_t Z_OFF   = 262144;
constexpr size_t FTH_B   = Z_OFF;
constexpr size_t FTL_B   = Z_OFF + 16777216;
constexpr size_t X0H_B   = Z_OFF + 33554432;
constexpr size_t X0L_B   = X0H_B + 33554432;
constexpr size_t X2H_B   = Z_OFF;                      // overlays featT+x0 (dead)
constexpr size_t X2L_B   = Z_OFF + 67108864;
constexpr size_t X1H_B   = Z_OFF + 134217728;
constexpr size_t X1L_B   = X1H_B + 33554432;
constexpr size_t WS_BIG  = X1L_B + 33554432;           // 201,588,736 B

__device__ __forceinline__ unsigned short f2bf(float x) {
    unsigned u = __float_as_uint(x);
    u += 0x7fffu + ((u >> 16) & 1u);           // RNE
    return (unsigned short)(u >> 16);
}
__device__ __forceinline__ float bf2f(unsigned short h) {
    return __uint_as_float((unsigned)h << 16);
}
__device__ __forceinline__ unsigned cvtpk(float a, float b) {
    unsigned r;
    asm("v_cvt_pk_bf16_f32 %0, %1, %2" : "=v"(r) : "v"(a), "v"(b));
    return r;
}
__device__ __forceinline__ void pack4(const float v[4], uint2& H, uint2& L) {
    H.x = cvtpk(v[0], v[1]);
    H.y = cvtpk(v[2], v[3]);
    const float r0 = v[0] - __uint_as_float(H.x << 16);
    const float r1 = v[1] - __uint_as_float(H.x & 0xffff0000u);
    const float r2 = v[2] - __uint_as_float(H.y << 16);
    const float r3 = v[3] - __uint_as_float(H.y & 0xffff0000u);
    L.x = cvtpk(r0, r1);
    L.y = cvtpk(r2, r3);
}
__device__ __forceinline__ f32x4 mfma3(short8 ah, short8 al, short8 bh, short8 bl, f32x4 acc) {
    acc = __builtin_amdgcn_mfma_f32_16x16x32_bf16(ah, bh, acc, 0, 0, 0);
    acc = __builtin_amdgcn_mfma_f32_16x16x32_bf16(ah, bl, acc, 0, 0, 0);
    acc = __builtin_amdgcn_mfma_f32_16x16x32_bf16(al, bh, acc, 0, 0, 0);
    return acc;
}

__global__ void copy_newxyz(const float* __restrict__ src, float* __restrict__ dst, int n) {
    int i = blockIdx.x * blockDim.x + threadIdx.x;
    if (i < n) dst[i] = src[i];
}

__global__ void prep_weights(const float* __restrict__ Wg, const float* __restrict__ W1,
                             const float* __restrict__ W2, const float* __restrict__ W3,
                             short* __restrict__ ws) {
    int i = blockIdx.x * blockDim.x + threadIdx.x;
    if (i >= 53248) return;
    float w; int hi, lo, j;
    if (i < 8192)       { j = i;         int o = j >> 7, c = j & 127; w = (c < 106) ? Wg[o * 106 + c] : 0.f; hi = WG_HI; lo = WG_LO; }
    else if (i < 12288) { j = i - 8192;  int o = j >> 6, c = j & 63;  w = W1[o * 64 + c];  hi = W1_HI; lo = W1_LO; }
    else if (i < 20480) { j = i - 12288; int o = j >> 6, c = j & 63;  w = W2[o * 64 + c];  hi = W2_HI; lo = W2_LO; }
    else                { j = i - 20480; int o = j >> 7, c = j & 127; w = W3[o * 128 + c]; hi = W3_HI; lo = W3_LO; }
    unsigned short h = f2bf(w);
    ws[hi + j] = (short)h;
    ws[lo + j] = (short)f2bf(w - bf2f(h));
}

__global__ __launch_bounds__(512) void prep_feat(const float* __restrict__ f,
                                                 short* __restrict__ ftH, short* __restrict__ ftL) {
    __shared__ float tile[kC][65];
    const int bb = blockIdx.x >> 8;
    const int n0 = (blockIdx.x & 255) * 64;
    const int tid = threadIdx.x;
    for (int c = tid >> 6; c < kC; c += 8)
        tile[c][tid & 63] = f[((size_t)bb * kC + c) * kN + n0 + (tid & 63)];
    __syncthreads();
    const int np = tid >> 3, gc = tid & 7;
    short* rH = ftH + ((size_t)bb * kN + n0 + np) * 128;
    short* rL = ftL + ((size_t)bb * kN + n0 + np) * 128;
    #pragma unroll
    for (int kk = 0; kk < 2; ++kk) {
        const int chunk = gc + 8 * kk;
        union { uint4 u; short s[8]; } H, L;
        #pragma unroll
        for (int e = 0; e < 8; ++e) {
            const int col = chunk * 8 + e;
            float v = (col >= 3 && col < 106) ? tile[col - 3][np] : 0.f;
            unsigned short hh = f2bf(v);
            H.s[e] = (short)hh;
            L.s[e] = (short)f2bf(v - bf2f(hh));
        }
        *(uint4*)(rH + chunk * 8) = H.u;
        *(uint4*)(rL + chunk * 8) = L.u;
    }
}

// ================= layered kernels =================
// frag maps (verified): A m=lane&15 (W row), k=8q+j; B n=lane&15 (point), k=8q+j;
// D n=lane&15 (point), m=4q+r (channel within 16-tile).

// K1: gather + gate -> x0 planes [N][64]. grid (512, 2); block 256 (4 waves x 8 iters x 16 pts)
__global__ __launch_bounds__(256, 3) void k1_gate(
    const float* __restrict__ xyz, const float* __restrict__ new_xyz,
    const int* __restrict__ idx, const short* __restrict__ wsw,
    const short* __restrict__ ftH, const short* __restrict__ ftL,
    const float* __restrict__ bg, short* __restrict__ x0H, short* __restrict__ x0L)
{
    const int lane = threadIdx.x & 63, wave = threadIdx.x >> 6;
    const int q = lane >> 4, n16 = lane & 15;
    const int gy = blockIdx.y;                 // o-pair: tiles {2gy, 2gy+1}
    const int pb = blockIdx.x * 512;
    const int b  = pb >> 16;
    short8 wh0[4], wl0[4], wh1[4], wl1[4];     // hoisted Wg frags (by-value SSA)
    #pragma unroll
    for (int kt = 0; kt < 4; ++kt) {
        const size_t w0 = (size_t)((2 * gy) * 16 + n16) * 128 + kt * 32 + q * 8;
        const size_t w1 = (size_t)((2 * gy + 1) * 16 + n16) * 128 + kt * 32 + q * 8;
        wh0[kt] = *(const short8*)(wsw + WG_HI + w0);
        wl0[kt] = *(const short8*)(wsw + WG_LO + w0);
        wh1[kt] = *(const short8*)(wsw + WG_HI + w1);
        wl1[kt] = *(const short8*)(wsw + WG_LO + w1);
    }
    const f32x4 bi0 = *(const f32x4*)(bg + (2 * gy) * 16 + 4 * q);
    const f32x4 bi1 = *(const f32x4*)(bg + (2 * gy + 1) * 16 + 4 * q);

    for (int it = 0; it < 8; ++it) {
        const int pt = pb + wave * 128 + it * 16 + n16;
        const int n  = idx[pt];
        const short* rH = ftH + ((size_t)b * kN + n) * 128;
        const short* rL = ftL + ((size_t)b * kN + n) * 128;
        float xd0 = 0.f, xd1 = 0.f, xd2 = 0.f;
        if (q == 0) {
            const float* xp = xyz + ((size_t)b * kN + n) * 3;
            const int pp = (pt >> 5) & (kP - 1);
            const float* np = new_xyz + ((size_t)b * kP + pp) * 3;
            xd0 = xp[0] - np[0]; xd1 = xp[1] - np[1]; xd2 = xp[2] - np[2];
        }
        short8 bh[4], bl[4];
        #pragma unroll
        for (int kt = 0; kt < 4; ++kt) {
            bh[kt] = *(const short8*)(rH + kt * 32 + q * 8);
            bl[kt] = *(const short8*)(rL + kt * 32 + q * 8);
        }
        if (q == 0) {
            const unsigned short h0 = f2bf(xd0), h1 = f2bf(xd1), h2 = f2bf(xd2);
            bh[0][0] = (short)h0; bh[0][1] = (short)h1; bh[0][2] = (short)h2;
            bl[0][0] = (short)f2bf(xd0 - bf2f(h0));
            bl[0][1] = (short)f2bf(xd1 - bf2f(h1));
            bl[0][2] = (short)f2bf(xd2 - bf2f(h2));
        }
        f32x4 a0 = bi0, a1 = bi1;
        #pragma unroll
        for (int kt = 0; kt < 4; ++kt) {
            a0 = mfma3(wh0[kt], wl0[kt], bh[kt], bl[kt], a0);
            a1 = mfma3(wh1[kt], wl1[kt], bh[kt], bl[kt], a1);
        }
        #pragma unroll
        for (int i = 0; i < 2; ++i) {
            const int ob = (2 * gy + i) * 16 + 4 * q;
            const uint2 BH = *(const uint2*)(rH + ob);
            const uint2 BL = *(const uint2*)(rL + ob);
            float base[4];
            base[0] = __uint_as_float(BH.x << 16)         + __uint_as_float(BL.x << 16);
            base[1] = __uint_as_float(BH.x & 0xffff0000u) + __uint_as_float(BL.x & 0xffff0000u);
            base[2] = __uint_as_float(BH.y << 16)         + __uint_as_float(BL.y << 16);
            base[3] = __uint_as_float(BH.y & 0xffff0000u) + __uint_as_float(BL.y & 0xffff0000u);
            if (gy == 0 && i == 0 && q == 0) { base[0] = xd0; base[1] = xd1; base[2] = xd2; }
            const f32x4 A = i ? a1 : a0;
            float v[4];
            #pragma unroll
            for (int r = 0; r < 4; ++r) v[r] = fmaf(base[r], A[r], base[r]);
            uint2 H, L;
            pack4(v, H, L);
            *(uint2*)(x0H + (size_t)pt * 64 + ob) = H;
            *(uint2*)(x0L + (size_t)pt * 64 + ob) = L;
        }
    }
}

// K2: layer1 (64->64), all o in wave. grid (512); block 256.
__global__ __launch_bounds__(256, 4) void k2_l1(
    const short* __restrict__ wsw, const short* __restrict__ x0H, const short* __restrict__ x0L,
    const float* __restrict__ b1f, short* __restrict__ x1H, short* __restrict__ x1L)
{
    const int lane = threadIdx.x & 63, wave = threadIdx.x >> 6;
    const int q = lane >> 4, n16 = lane & 15;
    const int pb = blockIdx.x * 512;
    short8 wh[8], wl[8];                        // [o][kt] flattened, static idx
    #pragma unroll
    for (int o = 0; o < 4; ++o)
        #pragma unroll
        for (int kt = 0; kt < 2; ++kt) {
            const size_t we = (size_t)(o * 16 + n16) * 64 + kt * 32 + q * 8;
            wh[o * 2 + kt] = *(const short8*)(wsw + W1_HI + we);
            wl[o * 2 + kt] = *(const short8*)(wsw + W1_LO + we);
        }
    for (int it = 0; it < 8; ++it) {
        const int pt = pb + wave * 128 + it * 16 + n16;
        short8 bh[2], bl[2];
        #pragma unroll
        for (int kt = 0; kt < 2; ++kt) {
            bh[kt] = *(const short8*)(x0H + (size_t)pt * 64 + kt * 32 + q * 8);
            bl[kt] = *(const short8*)(x0L + (size_t)pt * 64 + kt * 32 + q * 8);
        }
        #pragma unroll
        for (int o = 0; o < 4; ++o) {
            f32x4 a = *(const f32x4*)(b1f + o * 16 + 4 * q);
            #pragma unroll
            for (int kt = 0; kt < 2; ++kt)
                a = mfma3(wh[o * 2 + kt], wl[o * 2 + kt], bh[kt], bl[kt], a);
            float v[4];
            #pragma unroll
            for (int r = 0; r < 4; ++r) v[r] = fmaxf(a[r], 0.f);
            uint2 H, L;
            pack4(v, H, L);
            *(uint2*)(x1H + (size_t)pt * 64 + o * 16 + 4 * q) = H;
            *(uint2*)(x1L + (size_t)pt * 64 + o * 16 + 4 * q) = L;
        }
    }
}

// K3: layer2 (64->128), o-quads via grid.y. grid (512, 2); block 256.
__global__ __launch_bounds__(256, 4) void k3_l2(
    const short* __restrict__ wsw, const short* __restrict__ x1H, const short* __restrict__ x1L,
    const float* __restrict__ b2f, short* __restrict__ x2H, short* __restrict__ x2L)
{
    const int lane = threadIdx.x & 63, wave = threadIdx.x >> 6;
    const int q = lane >> 4, n16 = lane & 15;
    const int gy = blockIdx.y;                  // o-tiles {4gy .. 4gy+3}
    const int pb = blockIdx.x * 512;
    short8 wh[8], wl[8];
    #pragma unroll
    for (int o = 0; o < 4; ++o)
        #pragma unroll
        for (int kt = 0; kt < 2; ++kt) {
            const size_t we = (size_t)((4 * gy + o) * 16 + n16) * 64 + kt * 32 + q * 8;
            wh[o * 2 + kt] = *(const short8*)(wsw + W2_HI + we);
            wl[o * 2 + kt] = *(const short8*)(wsw + W2_LO + we);
        }
    for (int it = 0; it < 8; ++it) {
        const int pt = pb + wave * 128 + it * 16 + n16;
        short8 bh[2], bl[2];
        #pragma unroll
        for (int kt = 0; kt < 2; ++kt) {
            bh[kt] = *(const short8*)(x1H + (size_t)pt * 64 + kt * 32 + q * 8);
            bl[kt] = *(const short8*)(x1L + (size_t)pt * 64 + kt * 32 + q * 8);
        }
        #pragma unroll
        for (int o = 0; o < 4; ++o) {
            f32x4 a = *(const f32x4*)(b2f + (4 * gy + o) * 16 + 4 * q);
            #pragma unroll
            for (int kt = 0; kt < 2; ++kt)
                a = mfma3(wh[o * 2 + kt], wl[o * 2 + kt], bh[kt], bl[kt], a);
            float v[4];
            #pragma unroll
            for (int r = 0; r < 4; ++r) v[r] = fmaxf(a[r], 0.f);
            uint2 H, L;
            pack4(v, H, L);
            *(uint2*)(x2H + (size_t)pt * 128 + (4 * gy + o) * 16 + 4 * q) = H;
            *(uint2*)(x2L + (size_t)pt * 128 + (4 * gy + o) * 16 + 4 * q) = L;
        }
    }
}

// K4: layer3 (128->256) + s-pool. W3 o-half staged in LDS (swizzled). grid (256, 2); block 512.
__global__ __launch_bounds__(512, 2) void k4_l3(
    const short* __restrict__ wsw, const short* __restrict__ x2H, const short* __restrict__ x2L,
    const float* __restrict__ b3f, float* __restrict__ out_pooled)
{
    __shared__ alignas(16) short lds[32768];    // hi [128][128] @0, lo @16384
    const int tid = threadIdx.x, lane = tid & 63, wave = tid >> 6;
    const int q = lane >> 4, n16 = lane & 15;
    const int gy = blockIdx.y;                  // o-half: channels 128*gy ..+127
    #pragma unroll
    for (int k = 0; k < 4; ++k) {               // stage 2048 chunks/plane
        const int cid = tid + k * 512;
        const int row = cid >> 4, col = (cid & 15) * 8;
        const int swz = col ^ ((row & 7) << 3);
        *(short8*)(lds + row * 128 + swz) =
            *(const short8*)(wsw + W3_HI + (size_t)(128 * gy + row) * 128 + col);
        *(short8*)(lds + 16384 + row * 128 + swz) =
            *(const short8*)(wsw + W3_LO + (size_t)(128 * gy + row) * 128 + col);
    }
    __syncthreads();

    for (int it = 0; it < 4; ++it) {
        const int sg = blockIdx.x * 32 + wave * 4 + it;     // s-group = one (b,p)
        const size_t pt0 = (size_t)sg * 32;
        f32x4 acc[8][2];
        #pragma unroll
        for (int ot = 0; ot < 8; ++ot) {
            const f32x4 bi = *(const f32x4*)(b3f + 128 * gy + ot * 16 + 4 * q);
            acc[ot][0] = bi; acc[ot][1] = bi;
        }
        #pragma unroll
        for (int kt = 0; kt < 4; ++kt) {
            const int k0 = kt * 32 + q * 8;
            short8 bh[2], bl[2];
            #pragma unroll
            for (int j = 0; j < 2; ++j) {
                const size_t e = (pt0 + j * 16 + n16) * 128 + k0;
                bh[j] = *(const short8*)(x2H + e);
                bl[j] = *(const short8*)(x2L + e);
            }
            #pragma unroll
            for (int ot = 0; ot < 8; ++ot) {
                const int row = ot * 16 + n16;
                const int a = row * 128 + (k0 ^ ((row & 7) << 3));
                const short8 ah = *(const short8*)(lds + a);
                const short8 al = *(const short8*)(lds + 16384 + a);
                #pragma unroll
                for (int j = 0; j < 2; ++j)
                    acc[ot][j] = mfma3(ah, al, bh[j], bl[j], acc[ot][j]);
            }
        }
        const int p = sg & (kP - 1), bb = sg >> 11;
        float* outB = out_pooled + ((size_t)bb * 256 + 128 * gy) * kP + p;
        #pragma unroll
        for (int ot = 0; ot < 8; ++ot) {
            #pragma unroll
            for (int r = 0; r < 4; ++r) {
                float v = fmaxf(acc[ot][0][r], acc[ot][1][r]);
                v = fmaxf(v, __shfl_xor(v, 1, 16));
                v = fmaxf(v, __shfl_xor(v, 2, 16));
                v = fmaxf(v, __shfl_xor(v, 4, 16));
                v = fmaxf(v, __shfl_xor(v, 8, 16));
                v = fmaxf(v, 0.f);
                if (n16 == 0) outB[(size_t)(ot * 16 + 4 * q + r) * kP] = v;
            }
        }
    }
}

// ================= mid-tier fused kernel (v13, measured 183us) =================
template<int NOT, int NPT, int KT, int LDC, int LDW, bool INIT>
__device__ __forceinline__ void gemm_core(
    const short* __restrict__ xh, const short* __restrict__ xl,
    const short* __restrict__ wh, const short* __restrict__ wl,
    const float* __restrict__ bias, int kwoff,
    int ot0, int pt0t, int lane, f32x4 (&acc)[NOT][NPT])
{
    const int q = lane >> 4, n16 = lane & 15;
    if constexpr (INIT) {
        #pragma unroll
        for (int i = 0; i < NOT; ++i) {
            const f32x4 binit = *(const f32x4*)(bias + (ot0 + i) * 16 + 4 * q);
            #pragma unroll
            for (int j = 0; j < NPT; ++j) acc[i][j] = binit;
        }
    }
    #pragma unroll
    for (int kt = 0; kt < KT; ++kt) {
        const int k0 = kt * 32 + q * 8;
        short8 bh[NPT], bl[NPT];
        #pragma unroll
        for (int j = 0; j < NPT; ++j) {
            const int p = (pt0t + j) * 16 + n16;
            const int e = p * LDC + (k0 ^ ((p & 7) << 3));
            bh[j] = *(const short8*)(xh + e);
            bl[j] = *(const short8*)(xl + e);
        }
        #pragma unroll
        for (int i = 0; i < NOT; ++i) {
            const size_t we = (size_t)((ot0 + i) * 16 + n16) * LDW + kwoff + k0;
            const short8 ah = *(const short8*)(wh + we);
            const short8 al = *(const short8*)(wl + we);
            #pragma unroll
            for (int j = 0; j < NPT; ++j) acc[i][j] = mfma3(ah, al, bh[j], bl[j], acc[i][j]);
        }
    }
}

template<int NOT, int NPT, bool GATE, int LDCO>
__device__ __forceinline__ void store_act(
    f32x4 (&acc)[NOT][NPT], short* __restrict__ oh, short* __restrict__ ol,
    const short* __restrict__ nfh, const short* __restrict__ nfl,
    int ot0, int pt0t, int lane)
{
    const int q = lane >> 4, n16 = lane & 15;
    #pragma unroll
    for (int i = 0; i < NOT; ++i) {
        const int ob = (ot0 + i) * 16 + 4 * q;
        #pragma unroll
        for (int j = 0; j < NPT; ++j) {
            const int p = (pt0t + j) * 16 + n16;
            const int cs = ob ^ ((p & 7) << 3);
            float v[4];
            if (GATE) {
                const short4 h4 = *(const short4*)(nfh + p * 128 + cs);
                const short4 l4 = *(const short4*)(nfl + p * 128 + cs);
                #pragma unroll
                for (int r = 0; r < 4; ++r) {
                    const float base = bf2f((unsigned short)h4[r]) + bf2f((unsigned short)l4[r]);
                    v[r] = fmaf(base, acc[i][j][r], base);
                }
            } else {
                #pragma unroll
                for (int r = 0; r < 4; ++r) v[r] = fmaxf(acc[i][j][r], 0.f);
            }
            uint2 H, L;
            pack4(v, H, L);
            *(uint2*)(oh + p * LDCO + cs) = H;
            *(uint2*)(ol + p * LDCO + cs) = L;
        }
    }
}

template<bool DENSE>
__global__ __launch_bounds__(512, 2) void pointnet_sa(
    const float* __restrict__ xyz, const float* __restrict__ features,
    const float* __restrict__ new_xyz, const int* __restrict__ idx,
    const short* __restrict__ ws, const short* __restrict__ ftH, const short* __restrict__ ftL,
    const float* __restrict__ bg, const float* __restrict__ b1,
    const float* __restrict__ b2, const float* __restrict__ b3,
    float* __restrict__ out_pooled)
{
    __shared__ alignas(16) short smem[24576];
    short* NFh = smem;
    short* NFl = smem + 8192;
    short* X0h = smem + 16384;
    short* X0l = smem + 20480;

    const int tid = threadIdx.x, lane = tid & 63, wave = tid >> 6;
    const int q = lane >> 4, n16 = lane & 15;
    const int pt0 = blockIdx.x * 64;
    const int b = pt0 >> 16;

    if (DENSE) {
        const int gp = tid >> 3, gc = tid & 7;
        const int pt = pt0 + gp;
        const int n = idx[pt];
        const short* rH = ftH + ((size_t)b * kN + n) * 128;
        const short* rL = ftL + ((size_t)b * kN + n) * 128;
        uint4 hc0 = *(const uint4*)(rH + gc * 8);
        uint4 hc1 = *(const uint4*)(rH + gc * 8 + 64);
        uint4 lc0 = *(const uint4*)(rL + gc * 8);
        uint4 lc1 = *(const uint4*)(rL + gc * 8 + 64);
        if (gc == 0) {
            const float* xp = xyz + ((size_t)b * kN + n) * 3;
            const int pp = (pt >> 5) & (kP - 1);
            const float* np = new_xyz + ((size_t)b * kP + pp) * 3;
            union { uint4 u; short s[8]; } H, L;
            H.u = hc0; L.u = lc0;
            #pragma unroll
            for (int c = 0; c < 3; ++c) {
                const float v = xp[c] - np[c];
                const unsigned short hh = f2bf(v);
                H.s[c] = (short)hh;
                L.s[c] = (short)f2bf(v - bf2f(hh));
            }
            hc0 = H.u; lc0 = L.u;
        }
        const int sw = (gc ^ (gp & 7)) * 8;
        *(uint4*)(NFh + gp * 128 + sw)      = hc0;
        *(uint4*)(NFh + gp * 128 + sw + 64) = hc1;
        *(uint4*)(NFl + gp * 128 + sw)      = lc0;
        *(uint4*)(NFl + gp * 128 + sw + 64) = lc1;
    } else {
        const int p = tid & 63;
        const int cg = tid >> 6;
        const int pt = pt0 + p;
        const int n = idx[pt];
        const int pp = (pt >> 5) & (kP - 1);
        const float* fbp = features + (size_t)b * kC * kN + n;
        const float* xp = xyz + ((size_t)b * kN + n) * 3;
        const float* np = new_xyz + ((size_t)b * kP + pp) * 3;
        for (int c = cg; c < 128; c += 8) {
            float v;
            if (c < 3)        v = xp[c] - np[c];
            else if (c < 106) v = fbp[(size_t)(c - 3) * kN];
            else              v = 0.f;
            const unsigned short h = f2bf(v);
            const int cs = c ^ ((p & 7) << 3);
            NFh[p * 128 + cs] = (short)h;
            NFl[p * 128 + cs] = (short)f2bf(v - bf2f(h));
        }
    }
    __syncthreads();
    {
        f32x4 a[1][2];
        gemm_core<1, 2, 4, 128, 128, true>(NFh, NFl, ws + WG_HI, ws + WG_LO, bg, 0,
                                           wave & 3, 2 * (wave >> 2), lane, a);
        store_act<1, 2, true, 64>(a, X0h, X0l, NFh, NFl, wave & 3, 2 * (wave >> 2), lane);
    }
    __syncthreads();
    {
        f32x4 a[1][2];
        gemm_core<1, 2, 2, 64, 64, true>(X0h, X0l, ws + W1_HI, ws + W1_LO, b1, 0,
                                         wave & 3, 2 * (wave >> 2), lane, a);
        store_act<1, 2, false, 128>(a, NFh, NFl, nullptr, nullptr,
                                    wave & 3, 2 * (wave >> 2), lane);
    }
    __syncthreads();
    {
        f32x4 a[2][2];
        gemm_core<2, 2, 2, 128, 64, true>(NFh, NFl, ws + W2_HI, ws + W2_LO, b2, 0,
                                          2 * (wave & 3), 2 * (wave >> 2), lane, a);
        if ((wave & 3) < 2)
            store_act<2, 2, false, 64>(a, X0h, X0l, nullptr, nullptr,
                                       2 * (wave & 3), 2 * (wave >> 2), lane);
        else
            store_act<2, 2, false, 128>(a, NFh + 64, NFl + 64, nullptr, nullptr,
                                        (2 * (wave & 3)) & 3, 2 * (wave >> 2), lane);
    }
    __syncthreads();
    {
        f32x4 a[2][4];
        gemm_core<2, 4, 2, 64, 128, true >(X0h, X0l, ws + W3_HI, ws + W3_LO, b3, 0,
                                           2 * wave, 0, lane, a);
        gemm_core<2, 4, 2, 128, 128, false>(NFh + 64, NFl + 64, ws + W3_HI, ws + W3_LO,
                                            nullptr, 64, 2 * wave, 0, lane, a);
        #pragma unroll
        for (int i = 0; i < 2; ++i)
            #pragma unroll
            for (int sg = 0; sg < 2; ++sg)
                #pragma unroll
                for (int r = 0; r < 4; ++r) {
                    float v = fmaxf(a[i][2 * sg][r], a[i][2 * sg + 1][r]);
                    v = fmaxf(v, __shfl_xor(v, 1, 16));
                    v = fmaxf(v, __shfl_xor(v, 2, 16));
                    v = fmaxf(v, __shfl_xor(v, 4, 16));
                    v = fmaxf(v, __shfl_xor(v, 8, 16));
                    v = fmaxf(v, 0.f);
                    if (n16 == 0) {
                        const int o = (2 * wave + i) * 16 + 4 * q + r;
                        const int g = (pt0 >> 5) + sg;
                        out_pooled[((size_t)(g >> 11) * 256 + o) * kP + (g & (kP - 1))] = v;
                    }
                }
    }
}
}  // namespace

extern "C" void kernel_launch(void* const* d_in, const int* in_sizes, int n_in,
                              void* d_out, int out_size, void* d_ws, size_t ws_size,
                              hipStream_t stream) {
    const float* xyz      = (const float*)d_in[0];
    const float* features = (const float*)d_in[1];
    const float* new_xyz  = (const float*)d_in[2];
    const int*   idx      = (const int*)d_in[3];
    const float* Wg = (const float*)d_in[4];
    const float* bg = (const float*)d_in[5];
    const float* W1 = (const float*)d_in[6];
    const float* b1 = (const float*)d_in[7];
    const float* W2 = (const float*)d_in[8];
    const float* b2 = (const float*)d_in[9];
    const float* W3 = (const float*)d_in[10];
    const float* b3 = (const float*)d_in[11];
    float* out = (float*)d_out;
    short* wsw = (short*)d_ws;
    char*  wsb = (char*)d_ws;

    const int nxyz = kB * kP * 3;
    copy_newxyz<<<(nxyz + 255) / 256, 256, 0, stream>>>(new_xyz, out, nxyz);
    prep_weights<<<(53248 + 255) / 256, 256, 0, stream>>>(Wg, W1, W2, W3, wsw);
    float* pooled = out + nxyz;

    if (ws_size >= WS_BIG) {
        short* ftH = (short*)(wsb + FTH_B);
        short* ftL = (short*)(wsb + FTL_B);
        short* x0H = (short*)(wsb + X0H_B);
        short* x0L = (short*)(wsb + X0L_B);
        short* x1H = (short*)(wsb + X1H_B);
        short* x1L = (short*)(wsb + X1L_B);
        short* x2H = (short*)(wsb + X2H_B);
        short* x2L = (short*)(wsb + X2L_B);
        prep_feat<<<kB * (kN / 64), 512, 0, stream>>>(features, ftH, ftL);
        k1_gate<<<dim3(NPTS / 512, 2), 256, 0, stream>>>(xyz, new_xyz, idx, wsw,
                                                         ftH, ftL, bg, x0H, x0L);
        k2_l1<<<NPTS / 512, 256, 0, stream>>>(wsw, x0H, x0L, b1, x1H, x1L);
        k3_l2<<<dim3(NPTS / 512, 2), 256, 0, stream>>>(wsw, x1H, x1L, b2, x2H, x2L);
        k4_l3<<<dim3(NPTS / 1024, 2), 512, 0, stream>>>(wsw, x2H, x2L, b3, pooled);
    } else if (ws_size >= WS_NEED) {
        short* ftH = (short*)(wsb + FT_OFF);
        short* ftL = ftH + FT_SHORTS;
        prep_feat<<<kB * (kN / 64), 512, 0, stream>>>(features, ftH, ftL);
        pointnet_sa<true><<<(kB * kP * kS) / 64, 512, 0, stream>>>(
            xyz, features, new_xyz, idx, wsw, ftH, ftL, bg, b1, b2, b3, pooled);
    } else {
        pointnet_sa<false><<<(kB * kP * kS) / 64, 512, 0, stream>>>(
            xyz, features, new_xyz, idx, wsw, nullptr, nullptr, bg, b1, b2, b3, pooled);
    }
}

// Round 21
// 190.495 us; speedup vs baseline: 2.7418x; 2.4626x over previous
//
#include <hip/hip_runtime.h>
#include <stdint.h>

// PointNet SA via MFMA, v16 = v13 (best, 183us) + FORCED weight prefetch:
// gemm_core issues ALL weight global-loads + bias, then sched_barrier(0)
// (compiler cannot re-sink loads into the MFMA chain past the fence), then
// the ds_read+MFMA chain. v13's attempt failed silently (VGPR stayed 52 =
// loads re-sunk); the fence is the rule-18 tool that actually pins order.

namespace {
constexpr int kB = 4, kN = 16384, kC = 103, kP = 2048, kS = 32;

using short8 = __attribute__((ext_vector_type(8))) short;
using short4 = __attribute__((ext_vector_type(4))) short;
using f32x4  = __attribute__((ext_vector_type(4))) float;

constexpr int WG_HI = 0,     WG_LO = 8192;     // 64 x 128
constexpr int W1_HI = 16384, W1_LO = 20480;    // 64 x 64
constexpr int W2_HI = 24576, W2_LO = 32768;    // 128 x 64
constexpr int W3_HI = 40960, W3_LO = 73728;    // 256 x 128
constexpr size_t FT_OFF    = 262144;
constexpr size_t FT_SHORTS = (size_t)kB * kN * 128;
constexpr size_t WS_NEED   = FT_OFF + 2 * FT_SHORTS * 2;

__device__ __forceinline__ unsigned short f2bf(float x) {
    unsigned u = __float_as_uint(x);
    u += 0x7fffu + ((u >> 16) & 1u);           // RNE
    return (unsigned short)(u >> 16);
}
__device__ __forceinline__ float bf2f(unsigned short h) {
    return __uint_as_float((unsigned)h << 16);
}
__device__ __forceinline__ unsigned cvtpk(float a, float b) {
    unsigned r;
    asm("v_cvt_pk_bf16_f32 %0, %1, %2" : "=v"(r) : "v"(a), "v"(b));
    return r;
}
__device__ __forceinline__ void pack4(const float v[4], uint2& H, uint2& L) {
    H.x = cvtpk(v[0], v[1]);
    H.y = cvtpk(v[2], v[3]);
    const float r0 = v[0] - __uint_as_float(H.x << 16);
    const float r1 = v[1] - __uint_as_float(H.x & 0xffff0000u);
    const float r2 = v[2] - __uint_as_float(H.y << 16);
    const float r3 = v[3] - __uint_as_float(H.y & 0xffff0000u);
    L.x = cvtpk(r0, r1);
    L.y = cvtpk(r2, r3);
}
__device__ __forceinline__ f32x4 mfma3(short8 ah, short8 al, short8 bh, short8 bl, f32x4 acc) {
    acc = __builtin_amdgcn_mfma_f32_16x16x32_bf16(ah, bh, acc, 0, 0, 0);
    acc = __builtin_amdgcn_mfma_f32_16x16x32_bf16(ah, bl, acc, 0, 0, 0);
    acc = __builtin_amdgcn_mfma_f32_16x16x32_bf16(al, bh, acc, 0, 0, 0);
    return acc;
}

__global__ void copy_newxyz(const float* __restrict__ src, float* __restrict__ dst, int n) {
    int i = blockIdx.x * blockDim.x + threadIdx.x;
    if (i < n) dst[i] = src[i];
}

__global__ void prep_weights(const float* __restrict__ Wg, const float* __restrict__ W1,
                             const float* __restrict__ W2, const float* __restrict__ W3,
                             short* __restrict__ ws) {
    int i = blockIdx.x * blockDim.x + threadIdx.x;
    if (i >= 53248) return;
    float w; int hi, lo, j;
    if (i < 8192)       { j = i;         int o = j >> 7, c = j & 127; w = (c < 106) ? Wg[o * 106 + c] : 0.f; hi = WG_HI; lo = WG_LO; }
    else if (i < 12288) { j = i - 8192;  int o = j >> 6, c = j & 63;  w = W1[o * 64 + c];  hi = W1_HI; lo = W1_LO; }
    else if (i < 20480) { j = i - 12288; int o = j >> 6, c = j & 63;  w = W2[o * 64 + c];  hi = W2_HI; lo = W2_LO; }
    else                { j = i - 20480; int o = j >> 7, c = j & 127; w = W3[o * 128 + c]; hi = W3_HI; lo = W3_LO; }
    unsigned short h = f2bf(w);
    ws[hi + j] = (short)h;
    ws[lo + j] = (short)f2bf(w - bf2f(h));
}

__global__ __launch_bounds__(512) void prep_feat(const float* __restrict__ f,
                                                 short* __restrict__ ftH, short* __restrict__ ftL) {
    __shared__ float tile[kC][65];
    const int bb = blockIdx.x >> 8;
    const int n0 = (blockIdx.x & 255) * 64;
    const int tid = threadIdx.x;
    for (int c = tid >> 6; c < kC; c += 8)
        tile[c][tid & 63] = f[((size_t)bb * kC + c) * kN + n0 + (tid & 63)];
    __syncthreads();
    const int np = tid >> 3, gc = tid & 7;
    short* rH = ftH + ((size_t)bb * kN + n0 + np) * 128;
    short* rL = ftL + ((size_t)bb * kN + n0 + np) * 128;
    #pragma unroll
    for (int kk = 0; kk < 2; ++kk) {
        const int chunk = gc + 8 * kk;
        union { uint4 u; short s[8]; } H, L;
        #pragma unroll
        for (int e = 0; e < 8; ++e) {
            const int col = chunk * 8 + e;
            float v = (col >= 3 && col < 106) ? tile[col - 3][np] : 0.f;
            unsigned short hh = f2bf(v);
            H.s[e] = (short)hh;
            L.s[e] = (short)f2bf(v - bf2f(hh));
        }
        *(uint4*)(rH + chunk * 8) = H.u;
        *(uint4*)(rL + chunk * 8) = L.u;
    }
}

// A: m=lane&15 (W row), k=8*(lane>>4)+j; B: n=lane&15 (point), same k; D: n=lane&15, m=4*(lane>>4)+r
// All weight loads issue BEFORE sched_barrier(0); ds_read+MFMA chain after.
template<int NOT, int NPT, int KT, int LDC, int LDW, bool INIT>
__device__ __forceinline__ void gemm_core(
    const short* __restrict__ xh, const short* __restrict__ xl,
    const short* __restrict__ wh, const short* __restrict__ wl,
    const float* __restrict__ bias, int kwoff,
    int ot0, int pt0t, int lane, f32x4 (&acc)[NOT][NPT])
{
    const int q = lane >> 4, n16 = lane & 15;
    short8 whr[NOT * KT], wlr[NOT * KT];           // static-indexed SSA
    #pragma unroll
    for (int i = 0; i < NOT; ++i)
        #pragma unroll
        for (int kt = 0; kt < KT; ++kt) {
            const size_t we = (size_t)((ot0 + i) * 16 + n16) * LDW + kwoff + kt * 32 + q * 8;
            whr[i * KT + kt] = *(const short8*)(wh + we);
            wlr[i * KT + kt] = *(const short8*)(wl + we);
        }
    if constexpr (INIT) {
        #pragma unroll
        for (int i = 0; i < NOT; ++i) {
            const f32x4 binit = *(const f32x4*)(bias + (ot0 + i) * 16 + 4 * q);
            #pragma unroll
            for (int j = 0; j < NPT; ++j) acc[i][j] = binit;
        }
    }
    __builtin_amdgcn_sched_barrier(0);             // FENCE: loads stay issued above
    #pragma unroll
    for (int kt = 0; kt < KT; ++kt) {
        const int k0 = kt * 32 + q * 8;
        short8 bh[NPT], bl[NPT];
        #pragma unroll
        for (int j = 0; j < NPT; ++j) {
            const int p = (pt0t + j) * 16 + n16;
            const int e = p * LDC + (k0 ^ ((p & 7) << 3));
            bh[j] = *(const short8*)(xh + e);
            bl[j] = *(const short8*)(xl + e);
        }
        #pragma unroll
        for (int i = 0; i < NOT; ++i) {
            const short8 ah = whr[i * KT + kt];
            const short8 al = wlr[i * KT + kt];
            #pragma unroll
            for (int j = 0; j < NPT; ++j) acc[i][j] = mfma3(ah, al, bh[j], bl[j], acc[i][j]);
        }
    }
}

// GATE: v = base*(1+acc) with base from NF planes; else relu. cvt_pk packing.
template<int NOT, int NPT, bool GATE, int LDCO>
__device__ __forceinline__ void store_act(
    f32x4 (&acc)[NOT][NPT], short* __restrict__ oh, short* __restrict__ ol,
    const short* __restrict__ nfh, const short* __restrict__ nfl,
    int ot0, int pt0t, int lane)
{
    const int q = lane >> 4, n16 = lane & 15;
    #pragma unroll
    for (int i = 0; i < NOT; ++i) {
        const int ob = (ot0 + i) * 16 + 4 * q;
        #pragma unroll
        for (int j = 0; j < NPT; ++j) {
            const int p = (pt0t + j) * 16 + n16;
            const int cs = ob ^ ((p & 7) << 3);
            float v[4];
            if (GATE) {
                const short4 h4 = *(const short4*)(nfh + p * 128 + cs);
                const short4 l4 = *(const short4*)(nfl + p * 128 + cs);
                #pragma unroll
                for (int r = 0; r < 4; ++r) {
                    const float base = bf2f((unsigned short)h4[r]) + bf2f((unsigned short)l4[r]);
                    v[r] = fmaf(base, acc[i][j][r], base);      // base*(1+w)
                }
            } else {
                #pragma unroll
                for (int r = 0; r < 4; ++r) v[r] = fmaxf(acc[i][j][r], 0.f);
            }
            uint2 H, L;
            pack4(v, H, L);
            *(uint2*)(oh + p * LDCO + cs) = H;
            *(uint2*)(ol + p * LDCO + cs) = L;
        }
    }
}

template<bool DENSE>
__global__ __launch_bounds__(512, 2) void pointnet_sa(
    const float* __restrict__ xyz, const float* __restrict__ features,
    const float* __restrict__ new_xyz, const int* __restrict__ idx,
    const short* __restrict__ ws, const short* __restrict__ ftH, const short* __restrict__ ftL,
    const float* __restrict__ bg, const float* __restrict__ b1,
    const float* __restrict__ b2, const float* __restrict__ b3,
    float* __restrict__ out_pooled)  // (B, 256, P)
{
    __shared__ alignas(16) short smem[24576];      // 48 KB
    short* NFh = smem;                              // [64][128]
    short* NFl = smem + 8192;
    short* X0h = smem + 16384;                      // [64][64]
    short* X0l = smem + 20480;
    // X1 = NF cols 0-63 (stride 128); X2P = X0 region (stride 64); X2Q = NF cols 64-127

    const int tid = threadIdx.x, lane = tid & 63, wave = tid >> 6;
    const int q = lane >> 4, n16 = lane & 15;
    const int pt0 = blockIdx.x * 64;
    const int b = pt0 >> 16;

    if (DENSE) {
        const int gp = tid >> 3, gc = tid & 7;
        const int pt = pt0 + gp;
        const int n = idx[pt];
        const short* rH = ftH + ((size_t)b * kN + n) * 128;
        const short* rL = ftL + ((size_t)b * kN + n) * 128;
        uint4 hc0 = *(const uint4*)(rH + gc * 8);
        uint4 hc1 = *(const uint4*)(rH + gc * 8 + 64);
        uint4 lc0 = *(const uint4*)(rL + gc * 8);
        uint4 lc1 = *(const uint4*)(rL + gc * 8 + 64);
        if (gc == 0) {
            const float* xp = xyz + ((size_t)b * kN + n) * 3;
            const int pp = (pt >> 5) & (kP - 1);
            const float* np = new_xyz + ((size_t)b * kP + pp) * 3;
            union { uint4 u; short s[8]; } H, L;
            H.u = hc0; L.u = lc0;
            #pragma unroll
            for (int c = 0; c < 3; ++c) {
                const float v = xp[c] - np[c];
                const unsigned short hh = f2bf(v);
                H.s[c] = (short)hh;
                L.s[c] = (short)f2bf(v - bf2f(hh));
            }
            hc0 = H.u; lc0 = L.u;
        }
        const int sw = (gc ^ (gp & 7)) * 8;
        *(uint4*)(NFh + gp * 128 + sw)      = hc0;
        *(uint4*)(NFh + gp * 128 + sw + 64) = hc1;
        *(uint4*)(NFl + gp * 128 + sw)      = lc0;
        *(uint4*)(NFl + gp * 128 + sw + 64) = lc1;
    } else {
        const int p = tid & 63;
        const int cg = tid >> 6;
        const int pt = pt0 + p;
        const int n = idx[pt];
        const int pp = (pt >> 5) & (kP - 1);
        const float* fbp = features + (size_t)b * kC * kN + n;
        const float* xp = xyz + ((size_t)b * kN + n) * 3;
        const float* np = new_xyz + ((size_t)b * kP + pp) * 3;
        for (int c = cg; c < 128; c += 8) {
            float v;
            if (c < 3)        v = xp[c] - np[c];
            else if (c < 106) v = fbp[(size_t)(c - 3) * kN];
            else              v = 0.f;
            const unsigned short h = f2bf(v);
            const int cs = c ^ ((p & 7) << 3);
            NFh[p * 128 + cs] = (short)h;
            NFl[p * 128 + cs] = (short)f2bf(v - bf2f(h));
        }
    }
    __syncthreads();

    // ---- stage g ----
    {
        f32x4 a[1][2];
        gemm_core<1, 2, 4, 128, 128, true>(NFh, NFl, ws + WG_HI, ws + WG_LO, bg, 0,
                                           wave & 3, 2 * (wave >> 2), lane, a);
        store_act<1, 2, true, 64>(a, X0h, X0l, NFh, NFl, wave & 3, 2 * (wave >> 2), lane);
    }
    __syncthreads();                               // B1: NF dead

    // ---- stage 1 -> X1 in NF cols 0-63 ----
    {
        f32x4 a[1][2];
        gemm_core<1, 2, 2, 64, 64, true>(X0h, X0l, ws + W1_HI, ws + W1_LO, b1, 0,
                                         wave & 3, 2 * (wave >> 2), lane, a);
        store_act<1, 2, false, 128>(a, NFh, NFl, nullptr, nullptr,
                                    wave & 3, 2 * (wave >> 2), lane);
    }
    __syncthreads();                               // B2: X0 dead

    // ---- stage 2 -> X2 split ----
    {
        f32x4 a[2][2];
        gemm_core<2, 2, 2, 128, 64, true>(NFh, NFl, ws + W2_HI, ws + W2_LO, b2, 0,
                                          2 * (wave & 3), 2 * (wave >> 2), lane, a);
        if ((wave & 3) < 2)
            store_act<2, 2, false, 64>(a, X0h, X0l, nullptr, nullptr,
                                       2 * (wave & 3), 2 * (wave >> 2), lane);
        else
            store_act<2, 2, false, 128>(a, NFh + 64, NFl + 64, nullptr, nullptr,
                                        (2 * (wave & 3)) & 3, 2 * (wave >> 2), lane);
    }
    __syncthreads();                               // B3

    // ---- stage 3: K over X2P then X2Q + pool ----
    {
        f32x4 a[2][4];
        gemm_core<2, 4, 2, 64, 128, true >(X0h, X0l, ws + W3_HI, ws + W3_LO, b3, 0,
                                           2 * wave, 0, lane, a);
        gemm_core<2, 4, 2, 128, 128, false>(NFh + 64, NFl + 64, ws + W3_HI, ws + W3_LO,
                                            nullptr, 64, 2 * wave, 0, lane, a);
        #pragma unroll
        for (int i = 0; i < 2; ++i) {
            #pragma unroll
            for (int sg = 0; sg < 2; ++sg) {
                #pragma unroll
                for (int r = 0; r < 4; ++r) {
                    float v = fmaxf(a[i][2 * sg][r], a[i][2 * sg + 1][r]);
                    v = fmaxf(v, __shfl_xor(v, 1, 16));
                    v = fmaxf(v, __shfl_xor(v, 2, 16));
                    v = fmaxf(v, __shfl_xor(v, 4, 16));
                    v = fmaxf(v, __shfl_xor(v, 8, 16));
                    v = fmaxf(v, 0.f);
                    if (n16 == 0) {
                        const int o = (2 * wave + i) * 16 + 4 * q + r;
                        const int g = (pt0 >> 5) + sg;
                        out_pooled[((size_t)(g >> 11) * 256 + o) * kP + (g & (kP - 1))] = v;
                    }
                }
            }
        }
    }
}
}  // namespace

extern "C" void kernel_launch(void* const* d_in, const int* in_sizes, int n_in,
                              void* d_out, int out_size, void* d_ws, size_t ws_size,
                              hipStream_t stream) {
    const float* xyz      = (const float*)d_in[0];
    const float* features = (const float*)d_in[1];
    const float* new_xyz  = (const float*)d_in[2];
    const int*   idx      = (const int*)d_in[3];
    const float* Wg = (const float*)d_in[4];
    const float* bg = (const float*)d_in[5];
    const float* W1 = (const float*)d_in[6];
    const float* b1 = (const float*)d_in[7];
    const float* W2 = (const float*)d_in[8];
    const float* b2 = (const float*)d_in[9];
    const float* W3 = (const float*)d_in[10];
    const float* b3 = (const float*)d_in[11];
    float* out = (float*)d_out;
    short* ws  = (short*)d_ws;
    short* ftH = (short*)((char*)d_ws + FT_OFF);
    short* ftL = ftH + FT_SHORTS;

    const int nxyz = kB * kP * 3;
    copy_newxyz<<<(nxyz + 255) / 256, 256, 0, stream>>>(new_xyz, out, nxyz);
    prep_weights<<<(53248 + 255) / 256, 256, 0, stream>>>(Wg, W1, W2, W3, ws);

    float* pooled = out + nxyz;
    if (ws_size >= WS_NEED) {
        prep_feat<<<kB * (kN / 64), 512, 0, stream>>>(features, ftH, ftL);
        pointnet_sa<true><<<(kB * kP * kS) / 64, 512, 0, stream>>>(
            xyz, features, new_xyz, idx, ws, ftH, ftL, bg, b1, b2, b3, pooled);
    } else {
        pointnet_sa<false><<<(kB * kP * kS) / 64, 512, 0, stream>>>(
            xyz, features, new_xyz, idx, ws, nullptr, nullptr, bg, b1, b2, b3, pooled);
    }
}